// Round 1
// 1264.670 us; speedup vs baseline: 1.2108x; 1.2108x over previous
//
#include <hip/hip_runtime.h>

#define NN 100000
#define EE 600000
#define FF 512
#define HH 256
#define HD2 128

typedef unsigned short u16;
typedef unsigned int u32;
typedef __attribute__((ext_vector_type(4))) float f32x4;
typedef __attribute__((ext_vector_type(8))) short bf16x8;

__device__ __forceinline__ float bflo(u32 u){ return __uint_as_float(u << 16); }
__device__ __forceinline__ float bfhi(u32 u){ return __uint_as_float(u & 0xffff0000u); }
__device__ __forceinline__ u32 f2bf(float x){
  u32 u = __float_as_uint(x);
  return (u + 0x7FFFu + ((u >> 16) & 1u)) >> 16;
}
__device__ __forceinline__ u32 pack2(float x, float y){ return f2bf(x) | (f2bf(y) << 16); }

// ---------------- utility: zero ints ----------------
__global__ void zero_int_k(int* __restrict__ p, int n){
  int i = blockIdx.x * 256 + threadIdx.x;
  int st = gridDim.x * 256;
  for (; i < n; i += st) p[i] = 0;
}

// ---------------- degree count (int) ----------------
__global__ void count_deg_k(const int* __restrict__ dst, int* __restrict__ deg, int nE){
  int e = blockIdx.x * 256 + threadIdx.x;
  if (e < nE) atomicAdd(&deg[dst[e]], 1);
}

// ---------------- exclusive scan (1024 elems / block) ----------------
__global__ __launch_bounds__(256) void scan1_k(const int* __restrict__ deg, int* __restrict__ out,
                                               int* __restrict__ aux, int n){
  __shared__ int sm[256];
  const int t = threadIdx.x;
  const int base = blockIdx.x * 1024 + t * 4;
  int v0 = (base+0) < n ? deg[base+0] : 0;
  int v1 = (base+1) < n ? deg[base+1] : 0;
  int v2 = (base+2) < n ? deg[base+2] : 0;
  int v3 = (base+3) < n ? deg[base+3] : 0;
  int s = v0 + v1 + v2 + v3;
  sm[t] = s;
  __syncthreads();
  for (int off = 1; off < 256; off <<= 1){
    int x = (t >= off) ? sm[t - off] : 0;
    __syncthreads();
    sm[t] += x;
    __syncthreads();
  }
  if (t == 255) aux[blockIdx.x] = sm[255];
  int run = sm[t] - s;             // exclusive prefix within chunk
  if (base+0 < n) out[base+0] = run;            run += v0;
  if (base+1 < n) out[base+1] = run;            run += v1;
  if (base+2 < n) out[base+2] = run;            run += v2;
  if (base+3 < n) out[base+3] = run;
}
__global__ void scan2_k(int* __restrict__ aux, int nchunks){
  if (threadIdx.x == 0){
    int run = 0;
    for (int i = 0; i < nchunks; ++i){ int t = aux[i]; aux[i] = run; run += t; }
  }
}
__global__ void scan3_k(int* __restrict__ out, const int* __restrict__ aux, int n){
  int i = blockIdx.x * 256 + threadIdx.x;
  if (i < n) out[i] += aux[i >> 10];
}

// ---------------- CSR fill: csr[pos] = src of each edge, grouped by dst ----------------
__global__ void csr_fill_k(const int* __restrict__ src, const int* __restrict__ dst,
                           const int* __restrict__ rp, int* __restrict__ fill,
                           int* __restrict__ csr, int nE){
  int e = blockIdx.x * 256 + threadIdx.x;
  if (e >= nE) return;
  int d = dst[e];
  int pos = rp[d] + atomicAdd(&fill[d], 1);
  csr[pos] = src[e];
}

// ---------------- weight convert + transpose: W[k][n] f32 -> WT[n][k] bf16 ----------------
__global__ void wtcvt_k(const float* __restrict__ W, u16* __restrict__ WT,
                        int K, int nmask, int nshift, int total){
  int idx = blockIdx.x * 256 + threadIdx.x;
  if (idx >= total) return;
  int k = idx >> nshift, n = idx & nmask;
  WT[(size_t)n * K + k] = (u16)f2bf(W[idx]);
}

// ---------------- MFMA GEMM: C_bf16[M,256] = A_f32[M,512] @ B (BT bf16 [256][512]) ----------------
__global__ __launch_bounds__(256) void gemm_xw_k(
    const float* __restrict__ A, const u16* __restrict__ BT,
    u16* __restrict__ C, int M)
{
  __shared__ u16 As[128][40];   // [row][k], pad 40 (2-way banks for b128)
  __shared__ u16 Bs[128][40];   // [n][k]
  const int tid = threadIdx.x;
  const int w = tid >> 6, lane = tid & 63;
  const int row0 = blockIdx.x * 128, col0 = blockIdx.y * 128;
  const int wr = (w >> 1) * 64, wc = (w & 1) * 64;
  const int sar = tid >> 1, sak = (tid & 1) * 16;
  const int lrow = lane & 15, lk = (lane >> 4) * 8;
  f32x4 acc[4][4];
#pragma unroll
  for (int i = 0; i < 4; ++i)
#pragma unroll
    for (int j = 0; j < 4; ++j)
#pragma unroll
      for (int q = 0; q < 4; ++q) acc[i][j][q] = 0.f;

  const bool aval = (row0 + sar) < M;
  const float* apb = A + (size_t)(row0 + sar) * FF + sak;

  for (int kb = 0; kb < FF; kb += 32){
    if (aval){
      const float4* ap = (const float4*)(apb + kb);
      float4 v0 = ap[0], v1 = ap[1], v2 = ap[2], v3 = ap[3];
      uint4 p0 = make_uint4(pack2(v0.x,v0.y), pack2(v0.z,v0.w), pack2(v1.x,v1.y), pack2(v1.z,v1.w));
      uint4 p1 = make_uint4(pack2(v2.x,v2.y), pack2(v2.z,v2.w), pack2(v3.x,v3.y), pack2(v3.z,v3.w));
      *(uint4*)&As[sar][sak]     = p0;
      *(uint4*)&As[sar][sak + 8] = p1;
    } else {
      uint4 z = make_uint4(0,0,0,0);
      *(uint4*)&As[sar][sak]     = z;
      *(uint4*)&As[sar][sak + 8] = z;
    }
    for (int c = tid; c < 512; c += 256){
      int n = c >> 2, part = c & 3;
      uint4 bv = *(const uint4*)(BT + (size_t)(col0 + n) * FF + kb + part * 8);
      *(uint4*)&Bs[n][part * 8] = bv;
    }
    __syncthreads();
    bf16x8 af[4], bfr[4];
#pragma unroll
    for (int mt = 0; mt < 4; ++mt) af[mt]  = *(const bf16x8*)&As[wr + mt*16 + lrow][lk];
#pragma unroll
    for (int nt = 0; nt < 4; ++nt) bfr[nt] = *(const bf16x8*)&Bs[wc + nt*16 + lrow][lk];
#pragma unroll
    for (int mt = 0; mt < 4; ++mt)
#pragma unroll
      for (int nt = 0; nt < 4; ++nt)
        acc[mt][nt] = __builtin_amdgcn_mfma_f32_16x16x32_bf16(af[mt], bfr[nt], acc[mt][nt], 0, 0, 0);
    __syncthreads();
  }
  const int orow = (lane >> 4) * 4, ocol = lane & 15;
#pragma unroll
  for (int mt = 0; mt < 4; ++mt)
#pragma unroll
    for (int i = 0; i < 4; ++i){
      int r = row0 + wr + mt*16 + orow + i;
      if (r < M){
        u16* cp = C + (size_t)r * HH + col0 + wc + ocol;
#pragma unroll
        for (int nt = 0; nt < 4; ++nt)
          cp[nt * 16] = (u16)f2bf(acc[mt][nt][i]);
      }
    }
}

// ---------------- GCN CSR aggregate: H[d] = bias + xw[d]/(deg+1) + sum xw[s]*dis_s*dis_d ----------------
__global__ __launch_bounds__(256) void gcn_agg_k(
    const u16* __restrict__ XW, const int* __restrict__ rp,
    const int* __restrict__ deg, const int* __restrict__ csr,
    const float* __restrict__ bias, u16* __restrict__ H, int n)
{
  const int d = blockIdx.x * 4 + (threadIdx.x >> 6);
  if (d >= n) return;
  const int lane = threadIdx.x & 63;
  const int dg = deg[d];
  const float disd = rsqrtf((float)dg + 1.0f);
  const uint2* xw2 = (const uint2*)XW;
  uint2 sv = xw2[(size_t)d * 64 + lane];
  const float sw = disd * disd;
  float a0 = bflo(sv.x) * sw, a1 = bfhi(sv.x) * sw;
  float a2 = bflo(sv.y) * sw, a3 = bfhi(sv.y) * sw;
  const int s0 = rp[d], s1 = s0 + dg;
  for (int i = s0; i < s1; ++i){
    int s = csr[i];
    float wgt = rsqrtf((float)deg[s] + 1.0f) * disd;
    uint2 v = xw2[(size_t)s * 64 + lane];
    a0 = fmaf(bflo(v.x), wgt, a0); a1 = fmaf(bfhi(v.x), wgt, a1);
    a2 = fmaf(bflo(v.y), wgt, a2); a3 = fmaf(bfhi(v.y), wgt, a3);
  }
  const float4 bv = *(const float4*)(bias + lane * 4);
  a0 += bv.x; a1 += bv.y; a2 += bv.z; a3 += bv.w;
  uint2 o; o.x = pack2(a0, a1); o.y = pack2(a2, a3);
  ((uint2*)H)[(size_t)d * 64 + lane] = o;
}

// ---------------- SAGE CSR mean aggregate: M[d] = (sum X[s]) / max(deg,1) ----------------
__global__ __launch_bounds__(256) void sage_mean_k(
    const u16* __restrict__ X, const int* __restrict__ rp,
    const int* __restrict__ deg, const int* __restrict__ csr,
    u16* __restrict__ Mo, int n)
{
  const int d = blockIdx.x * 4 + (threadIdx.x >> 6);
  if (d >= n) return;
  const int lane = threadIdx.x & 63;
  const int dg = deg[d];
  const uint2* x2 = (const uint2*)X;
  float a0 = 0.f, a1 = 0.f, a2 = 0.f, a3 = 0.f;
  const int s0 = rp[d], s1 = s0 + dg;
  for (int i = s0; i < s1; ++i){
    int s = csr[i];
    uint2 v = x2[(size_t)s * 64 + lane];
    a0 += bflo(v.x); a1 += bfhi(v.x);
    a2 += bflo(v.y); a3 += bfhi(v.y);
  }
  const float sc = 1.0f / (float)(dg > 0 ? dg : 1);
  uint2 o; o.x = pack2(a0 * sc, a1 * sc); o.y = pack2(a2 * sc, a3 * sc);
  ((uint2*)Mo)[(size_t)d * 64 + lane] = o;
}

// ---------------- combine: X0 = relu(h)+relu(g); G1 = relu(g)+g (bf16 pairs) ----------------
__global__ void combine_k(u32* __restrict__ X0, u32* __restrict__ G1,
                          const u32* __restrict__ H1, const u32* __restrict__ H2)
{
  int i = blockIdx.x * 256 + threadIdx.x;
  u32 uh = H1[i], ug = H2[i];
  float h0 = bflo(uh), h1 = bfhi(uh), g0 = bflo(ug), g1 = bfhi(ug);
  float rh0 = fmaxf(h0, 0.f), rh1 = fmaxf(h1, 0.f);
  float rg0 = fmaxf(g0, 0.f), rg1 = fmaxf(g1, 0.f);
  X0[i] = pack2(rh0 + rg0, rh1 + rg1);
  G1[i] = pack2(rg0 + g0, rg1 + g1);
}

// ---------------- SAGE MFMA GEMM: S = relu(A1@B1 + A2@B2 + bias), all bf16, N=128 ----------------
__global__ __launch_bounds__(256) void sage_gemm_k(
    const u16* __restrict__ A1, const u16* __restrict__ A2,
    const u16* __restrict__ B1T, const u16* __restrict__ B2T,
    const float* __restrict__ bias, u16* __restrict__ S, int M)
{
  __shared__ u16 As[128][40];
  __shared__ u16 Bs[128][40];
  const int tid = threadIdx.x;
  const int w = tid >> 6, lane = tid & 63;
  const int row0 = blockIdx.x * 128;
  const int wr = (w >> 1) * 64, wc = (w & 1) * 64;
  const int lrow = lane & 15, lk = (lane >> 4) * 8;
  f32x4 acc[4][4];
#pragma unroll
  for (int i = 0; i < 4; ++i)
#pragma unroll
    for (int j = 0; j < 4; ++j)
#pragma unroll
      for (int q = 0; q < 4; ++q) acc[i][j][q] = 0.f;

  for (int pass = 0; pass < 2; ++pass){
    const u16* Ap = pass ? A2 : A1;
    const u16* Bp = pass ? B2T : B1T;
    for (int kb = 0; kb < HH; kb += 32){
      for (int c = tid; c < 512; c += 256){
        int r = c >> 2, part = c & 3;
        int grow = row0 + r;
        uint4 v = make_uint4(0,0,0,0);
        if (grow < M) v = *(const uint4*)(Ap + (size_t)grow * HH + kb + part * 8);
        *(uint4*)&As[r][part * 8] = v;
      }
      for (int c = tid; c < 512; c += 256){
        int n = c >> 2, part = c & 3;
        uint4 v = *(const uint4*)(Bp + (size_t)n * HH + kb + part * 8);
        *(uint4*)&Bs[n][part * 8] = v;
      }
      __syncthreads();
      bf16x8 af[4], bfr[4];
#pragma unroll
      for (int mt = 0; mt < 4; ++mt) af[mt]  = *(const bf16x8*)&As[wr + mt*16 + lrow][lk];
#pragma unroll
      for (int nt = 0; nt < 4; ++nt) bfr[nt] = *(const bf16x8*)&Bs[wc + nt*16 + lrow][lk];
#pragma unroll
      for (int mt = 0; mt < 4; ++mt)
#pragma unroll
        for (int nt = 0; nt < 4; ++nt)
          acc[mt][nt] = __builtin_amdgcn_mfma_f32_16x16x32_bf16(af[mt], bfr[nt], acc[mt][nt], 0, 0, 0);
      __syncthreads();
    }
  }
  const int orow = (lane >> 4) * 4, ocol = lane & 15;
#pragma unroll
  for (int mt = 0; mt < 4; ++mt)
#pragma unroll
    for (int i = 0; i < 4; ++i){
      int r = row0 + wr + mt*16 + orow + i;
      if (r < M){
        u16* cp = S + (size_t)r * HD2 + wc + ocol;
#pragma unroll
        for (int nt = 0; nt < 4; ++nt){
          float v = acc[mt][nt][i] + bias[wc + nt*16 + ocol];
          cp[nt * 16] = (u16)f2bf(fmaxf(v, 0.f));
        }
      }
    }
}

// ---------------- fused MLP (MFMA) + LayerNorm + dot(Wm2) -> per-block f64 partial ----------------
// Swapped-operand MFMA: A = Wm1^T (j rows), B = X^T (node cols).
// Lane (g = lane>>4, cn = lane&15) holds h[j] for node = base+cn at
// j = jt*16 + g*4 + r  (jt = 0..7, r = 0..3).  Row-reduce = 32 per-lane + shfl_xor(16,32).
// LN+dot algebra: p = rs*(sum_j h_j*c1_j - mu*S1) + C0 + bm2,
//   c1_j = lnw_j*w2_j, S1 = sum c1, C0 = sum lnb_j*w2_j.
__global__ __launch_bounds__(256) void mlp_mfma_k(
    const u16* __restrict__ Xin,       // [M][128] bf16 rows
    const u16* __restrict__ W1T,       // [128][128] bf16: W1T[j*128+k] = Wm1[k][j]
    const float* __restrict__ bm1,
    const float* __restrict__ lnw, const float* __restrict__ lnb,
    const float* __restrict__ Wm2, const float* __restrict__ bm2,
    double* __restrict__ partial, int M)
{
  __shared__ u16 Wsh[HD2][136];        // pad row to 272B: 2-way bank alias only (free)
  __shared__ double wsum[4];
  const int tid = threadIdx.x;
  const int lane = tid & 63, wv = tid >> 6;
  const int g = lane >> 4, cn = lane & 15;

  // stage Wm1^T into LDS (16B chunks, coalesced; 8 iters)
  for (int i = tid; i < HD2 * 16; i += 256){
    int j = i >> 4, c = i & 15;
    *(uint4*)&Wsh[j][c * 8] = ((const uint4*)W1T)[i];
  }

  // per-lane epilogue constants: j = jt*16 + g*4 + r
  f32x4 b1v[8], c1v[8];
  float S1 = 0.f, C0 = 0.f;
#pragma unroll
  for (int jt = 0; jt < 8; ++jt){
    int j = jt * 16 + g * 4;
    float4 bb = *(const float4*)&bm1[j];
    float4 lw = *(const float4*)&lnw[j];
    float4 lb = *(const float4*)&lnb[j];
    float4 w2 = *(const float4*)&Wm2[j];
    b1v[jt][0] = bb.x; b1v[jt][1] = bb.y; b1v[jt][2] = bb.z; b1v[jt][3] = bb.w;
    c1v[jt][0] = lw.x * w2.x; c1v[jt][1] = lw.y * w2.y;
    c1v[jt][2] = lw.z * w2.z; c1v[jt][3] = lw.w * w2.w;
    S1 += c1v[jt][0] + c1v[jt][1] + c1v[jt][2] + c1v[jt][3];
    C0 += lb.x * w2.x + lb.y * w2.y + lb.z * w2.z + lb.w * w2.w;
  }
  // each g-group covers a disjoint quarter of j: sum the 4 groups
  S1 += __shfl_xor(S1, 16); S1 += __shfl_xor(S1, 32);
  C0 += __shfl_xor(C0, 16); C0 += __shfl_xor(C0, 32);
  const float bm2v = bm2[0];
  __syncthreads();

  double local = 0.0;
  const int stride = gridDim.x * 64;
  for (int base = blockIdx.x * 64 + wv * 16; base < M; base += stride){
    const int node = base + cn;
    const bool nv = node < M;
    f32x4 acc[8];
#pragma unroll
    for (int jt = 0; jt < 8; ++jt){ acc[jt][0]=0.f; acc[jt][1]=0.f; acc[jt][2]=0.f; acc[jt][3]=0.f; }
#pragma unroll
    for (int ks = 0; ks < 4; ++ks){
      bf16x8 bfv = {0,0,0,0,0,0,0,0};
      if (nv) bfv = *(const bf16x8*)(Xin + (size_t)node * HD2 + ks * 32 + g * 8);
#pragma unroll
      for (int jt = 0; jt < 8; ++jt){
        bf16x8 afr = *(const bf16x8*)&Wsh[jt * 16 + cn][ks * 32 + g * 8];
        acc[jt] = __builtin_amdgcn_mfma_f32_16x16x32_bf16(afr, bfv, acc[jt], 0, 0, 0);
      }
    }
    // h = acc + bm1; mean
    float s = 0.f;
#pragma unroll
    for (int jt = 0; jt < 8; ++jt){
#pragma unroll
      for (int r = 0; r < 4; ++r){
        acc[jt][r] += b1v[jt][r];
        s += acc[jt][r];
      }
    }
    s += __shfl_xor(s, 16); s += __shfl_xor(s, 32);
    const float mu = s * (1.0f / HD2);
    // variance + fused dot
    float vs = 0.f, d1 = 0.f;
#pragma unroll
    for (int jt = 0; jt < 8; ++jt){
#pragma unroll
      for (int r = 0; r < 4; ++r){
        float dv = acc[jt][r] - mu;
        vs = fmaf(dv, dv, vs);
        d1 = fmaf(acc[jt][r], c1v[jt][r], d1);
      }
    }
    vs += __shfl_xor(vs, 16); vs += __shfl_xor(vs, 32);
    d1 += __shfl_xor(d1, 16); d1 += __shfl_xor(d1, 32);
    const float rs = rsqrtf(vs * (1.0f / HD2) + 1e-5f);
    const float p = rs * (d1 - mu * S1) + C0 + bm2v;
    if (nv && g == 0) local += (double)p;   // count each node once
  }
  // wave butterfly over f64 (lanes g>0 carry 0)
#pragma unroll
  for (int off = 32; off > 0; off >>= 1) local += __shfl_xor(local, off);
  if (lane == 0) wsum[wv] = local;
  __syncthreads();
  if (tid == 0) partial[blockIdx.x] = wsum[0] + wsum[1] + wsum[2] + wsum[3];
}

// ---------------- final: sum 1024 f64 partials, dtype-robust output word ----------------
__global__ __launch_bounds__(256) void final_reduce_k(
    const double* __restrict__ P, u32* __restrict__ out)
{
  __shared__ double sm[256];
  const int tid = threadIdx.x;
  double s = P[tid] + P[tid + 256] + P[tid + 512] + P[tid + 768];
  sm[tid] = s;
  __syncthreads();
  for (int h = 128; h > 0; h >>= 1){
    if (tid < h) sm[tid] += sm[tid + h];
    __syncthreads();
  }
  if (tid == 0){
    float v = (float)(sm[0] * (1.0 / (2.0 * (double)NN)));
    u32 bf = f2bf(v);
    out[0] = (bf << 16) | bf;   // fp32 reader ~v; bf16 reader low half exact
  }
}

extern "C" void kernel_launch(void* const* d_in, const int* in_sizes, int n_in,
                              void* d_out, int out_size, void* d_ws, size_t ws_size,
                              hipStream_t stream)
{
  const float* x   = (const float*)d_in[0];
  const float* x1  = (const float*)d_in[1];
  const int* ei  = (const int*)d_in[2];
  const int* ei1 = (const int*)d_in[3];
  const float* Wg1 = (const float*)d_in[4];
  const float* bg1 = (const float*)d_in[5];
  const float* Wg2 = (const float*)d_in[6];
  const float* bg2 = (const float*)d_in[7];
  const float* Wl1 = (const float*)d_in[8];
  const float* bl1 = (const float*)d_in[9];
  const float* Wr1 = (const float*)d_in[10];
  const float* Wl2 = (const float*)d_in[11];
  const float* bl2 = (const float*)d_in[12];
  const float* Wr2 = (const float*)d_in[13];
  const float* Wm1 = (const float*)d_in[14];
  const float* bm1 = (const float*)d_in[15];
  const float* lnw = (const float*)d_in[16];
  const float* lnb = (const float*)d_in[17];
  const float* Wm2 = (const float*)d_in[18];
  const float* bm2 = (const float*)d_in[19];

  const int* src1 = ei,  * dst1 = ei + EE;
  const int* src2 = ei1, * dst2 = ei1 + EE;

  // ---- workspace layout (bf16 node features + CSR + partials), ~264 MB ----
  u16* U0 = (u16*)d_ws;                        // XW1 -> X0     [NN*HH]
  u16* U1 = U0 + (size_t)NN * HH;              // XW2 -> G1
  u16* U2 = U1 + (size_t)NN * HH;              // H1  -> M1
  u16* U3 = U2 + (size_t)NN * HH;              // H2  -> M2
  u16* U4 = U3 + (size_t)NN * HH;              // S1 [NN*HD2]
  u16* U5 = U4 + (size_t)NN * HD2;             // S2 (contiguous after S1)
  u16* WG1T = U5 + (size_t)NN * HD2;           // [HH][FF]
  u16* WG2T = WG1T + HH * FF;
  u16* WL1T = WG2T + HH * FF;                  // [HD2][HH]
  u16* WR1T = WL1T + HD2 * HH;
  u16* WL2T = WR1T + HD2 * HH;
  u16* WR2T = WL2T + HD2 * HH;
  int* deg1 = (int*)(WR2T + HD2 * HH);
  int* deg2 = deg1 + NN;
  int* fill1 = deg2 + NN;
  int* fill2 = fill1 + NN;
  int* rp1 = fill2 + NN;
  int* rp2 = rp1 + NN;
  int* aux1 = rp2 + NN;
  int* aux2 = aux1 + 128;
  int* csr1 = aux2 + 128;
  int* csr2 = csr1 + EE;
  double* P = (double*)(csr2 + EE);            // 1024 doubles (8B-aligned)
  u16* WM1T = U0;                              // reuse U0 after sage GEMMs (stream-serial)

  const int eblk = (EE + 255) / 256;
  const int nchunks = (NN + 1023) / 1024;      // 98

  // ---- CSR build (both graphs) ----
  zero_int_k<<<512, 256, 0, stream>>>(deg1, 4 * NN);   // deg1,deg2,fill1,fill2
  count_deg_k<<<eblk, 256, 0, stream>>>(dst1, deg1, EE);
  count_deg_k<<<eblk, 256, 0, stream>>>(dst2, deg2, EE);
  scan1_k<<<nchunks, 256, 0, stream>>>(deg1, rp1, aux1, NN);
  scan1_k<<<nchunks, 256, 0, stream>>>(deg2, rp2, aux2, NN);
  scan2_k<<<1, 64, 0, stream>>>(aux1, nchunks);
  scan2_k<<<1, 64, 0, stream>>>(aux2, nchunks);
  scan3_k<<<(NN + 255) / 256, 256, 0, stream>>>(rp1, aux1, NN);
  scan3_k<<<(NN + 255) / 256, 256, 0, stream>>>(rp2, aux2, NN);
  csr_fill_k<<<eblk, 256, 0, stream>>>(src1, dst1, rp1, fill1, csr1, EE);
  csr_fill_k<<<eblk, 256, 0, stream>>>(src2, dst2, rp2, fill2, csr2, EE);

  // ---- weight convert+transpose ----
  wtcvt_k<<<512, 256, 0, stream>>>(Wg1, WG1T, FF, HH - 1, 8, FF * HH);
  wtcvt_k<<<512, 256, 0, stream>>>(Wg2, WG2T, FF, HH - 1, 8, FF * HH);
  wtcvt_k<<<128, 256, 0, stream>>>(Wl1, WL1T, HH, HD2 - 1, 7, HH * HD2);
  wtcvt_k<<<128, 256, 0, stream>>>(Wr1, WR1T, HH, HD2 - 1, 7, HH * HD2);
  wtcvt_k<<<128, 256, 0, stream>>>(Wl2, WL2T, HH, HD2 - 1, 7, HH * HD2);
  wtcvt_k<<<128, 256, 0, stream>>>(Wr2, WR2T, HH, HD2 - 1, 7, HH * HD2);

  // ---- GCN linear (MFMA) ----
  dim3 ggrid((NN + 127) / 128, HH / 128);      // (782, 2)
  gemm_xw_k<<<ggrid, 256, 0, stream>>>(x,  WG1T, U0, NN);
  gemm_xw_k<<<ggrid, 256, 0, stream>>>(x1, WG2T, U1, NN);

  // ---- GCN aggregate (CSR gather, fused self-loop + bias) ----
  gcn_agg_k<<<NN / 4, 256, 0, stream>>>(U0, rp1, deg1, csr1, bg1, U2, NN);
  gcn_agg_k<<<NN / 4, 256, 0, stream>>>(U1, rp2, deg2, csr2, bg2, U3, NN);

  // ---- combine ----
  combine_k<<<NN * HH / 512, 256, 0, stream>>>((u32*)U0, (u32*)U1, (const u32*)U2, (const u32*)U3);

  // ---- SAGE mean aggregate (CSR gather, fused mean) ----
  sage_mean_k<<<NN / 4, 256, 0, stream>>>(U0, rp1, deg1, csr1, U2, NN);
  sage_mean_k<<<NN / 4, 256, 0, stream>>>(U1, rp2, deg2, csr2, U3, NN);

  // ---- SAGE linear (MFMA, two K-passes) + relu ----
  sage_gemm_k<<<(NN + 127) / 128, 256, 0, stream>>>(U2, U0, WL1T, WR1T, bl1, U4, NN);
  sage_gemm_k<<<(NN + 127) / 128, 256, 0, stream>>>(U3, U1, WL2T, WR2T, bl2, U5, NN);

  // ---- Wm1^T bf16 (into U0, free after the sage GEMMs) ----
  wtcvt_k<<<64, 256, 0, stream>>>(Wm1, WM1T, HD2, HD2 - 1, 7, HD2 * HD2);

  // ---- fused MLP + LN + reduce over both halves (U4||U5 contiguous, M = 2N) ----
  mlp_mfma_k<<<1024, 256, 0, stream>>>(U4, WM1T, bm1, lnw, lnb, Wm2, bm2, P, 2 * NN);

  final_reduce_k<<<1, 256, 0, stream>>>(P, (u32*)d_out);
}

// Round 2
// 1234.136 us; speedup vs baseline: 1.2408x; 1.0247x over previous
//
#include <hip/hip_runtime.h>

#define NN 100000
#define EE 600000
#define FF 512
#define HH 256
#define HD2 128

typedef unsigned short u16;
typedef unsigned int u32;
typedef __attribute__((ext_vector_type(4))) float f32x4;
typedef __attribute__((ext_vector_type(8))) short bf16x8;
typedef __attribute__((ext_vector_type(4))) unsigned int u32x4;

__device__ __forceinline__ float bflo(u32 u){ return __uint_as_float(u << 16); }
__device__ __forceinline__ float bfhi(u32 u){ return __uint_as_float(u & 0xffff0000u); }
__device__ __forceinline__ u32 f2bf(float x){
  u32 u = __float_as_uint(x);
  return (u + 0x7FFFu + ((u >> 16) & 1u)) >> 16;
}
__device__ __forceinline__ u32 pack2(float x, float y){ return f2bf(x) | (f2bf(y) << 16); }

// async global->LDS, 16B per lane, linear dest (wave-uniform base + lane*16)
__device__ __forceinline__ void gll16(const void* g, void* l){
  __builtin_amdgcn_global_load_lds((const __attribute__((address_space(1))) void*)g,
                                   (__attribute__((address_space(3))) void*)l, 16, 0, 0);
}
// packed f32x2 -> bf16x2 (RNE), CDNA4; no builtin exists (T12)
__device__ __forceinline__ u32 cvtpk(float lo, float hi){
  u32 r;
  asm("v_cvt_pk_bf16_f32 %0, %1, %2" : "=v"(r) : "v"(lo), "v"(hi));
  return r;
}

// ---------------- utility: zero ints ----------------
__global__ void zero_int_k(int* __restrict__ p, int n){
  int i = blockIdx.x * 256 + threadIdx.x;
  int st = gridDim.x * 256;
  for (; i < n; i += st) p[i] = 0;
}

// ---------------- degree count (int) ----------------
__global__ void count_deg_k(const int* __restrict__ dst, int* __restrict__ deg, int nE){
  int e = blockIdx.x * 256 + threadIdx.x;
  if (e < nE) atomicAdd(&deg[dst[e]], 1);
}

// ---------------- exclusive scan (1024 elems / block) ----------------
__global__ __launch_bounds__(256) void scan1_k(const int* __restrict__ deg, int* __restrict__ out,
                                               int* __restrict__ aux, int n){
  __shared__ int sm[256];
  const int t = threadIdx.x;
  const int base = blockIdx.x * 1024 + t * 4;
  int v0 = (base+0) < n ? deg[base+0] : 0;
  int v1 = (base+1) < n ? deg[base+1] : 0;
  int v2 = (base+2) < n ? deg[base+2] : 0;
  int v3 = (base+3) < n ? deg[base+3] : 0;
  int s = v0 + v1 + v2 + v3;
  sm[t] = s;
  __syncthreads();
  for (int off = 1; off < 256; off <<= 1){
    int x = (t >= off) ? sm[t - off] : 0;
    __syncthreads();
    sm[t] += x;
    __syncthreads();
  }
  if (t == 255) aux[blockIdx.x] = sm[255];
  int run = sm[t] - s;             // exclusive prefix within chunk
  if (base+0 < n) out[base+0] = run;            run += v0;
  if (base+1 < n) out[base+1] = run;            run += v1;
  if (base+2 < n) out[base+2] = run;            run += v2;
  if (base+3 < n) out[base+3] = run;
}
__global__ void scan2_k(int* __restrict__ aux, int nchunks){
  if (threadIdx.x == 0){
    int run = 0;
    for (int i = 0; i < nchunks; ++i){ int t = aux[i]; aux[i] = run; run += t; }
  }
}
__global__ void scan3_k(int* __restrict__ out, const int* __restrict__ aux, int n){
  int i = blockIdx.x * 256 + threadIdx.x;
  if (i < n) out[i] += aux[i >> 10];
}

// ---------------- CSR fill: csr[pos] = src of each edge, grouped by dst ----------------
__global__ void csr_fill_k(const int* __restrict__ src, const int* __restrict__ dst,
                           const int* __restrict__ rp, int* __restrict__ fill,
                           int* __restrict__ csr, int nE){
  int e = blockIdx.x * 256 + threadIdx.x;
  if (e >= nE) return;
  int d = dst[e];
  int pos = rp[d] + atomicAdd(&fill[d], 1);
  csr[pos] = src[e];
}

// ---------------- weight convert + transpose: W[k][n] f32 -> WT[n][k] bf16 ----------------
__global__ void wtcvt_k(const float* __restrict__ W, u16* __restrict__ WT,
                        int K, int nmask, int nshift, int total){
  int idx = blockIdx.x * 256 + threadIdx.x;
  if (idx >= total) return;
  int k = idx >> nshift, n = idx & nmask;
  WT[(size_t)n * K + k] = (u16)f2bf(W[idx]);
}

// ---------------- MFMA GEMM: C_bf16[M,256] = A_f32[M,512] @ B (BT bf16 [256][512]) ----------
// 2-phase double-buffered global_load_lds pipeline (T3-min), 16B-chunk XOR swizzle (T2, rule#21):
//   storage chunk S = L ^ ((L>>3)&7), involution; global source inverse-swizzled, ds_read swizzled.
// A stays f32 in LDS; f32->bf16 via v_cvt_pk_bf16_f32 at fragment build (1 VALU / pair).
__global__ __launch_bounds__(256) void gemm_xw_k(
    const float* __restrict__ A, const u16* __restrict__ BT,
    u16* __restrict__ C, int M)
{
  __shared__ float As[2][4096];   // 16 KB per buf: [128 rows][32 k] f32, swizzled chunks
  __shared__ u16  Bs[2][4096];    // 8 KB per buf: [128 cols][32 k] bf16, swizzled chunks
  const int tid = threadIdx.x;
  const int w = tid >> 6, lane = tid & 63;
  const int row0 = blockIdx.x * 128, col0 = blockIdx.y * 128;
  const int wr = (w >> 1) * 64, wc = (w & 1) * 64;
  const int lrow = lane & 15, g = lane >> 4;   // fragment row, k-group

  // ---- staging descriptors (per-lane global byte offsets; LDS dests wave-uniform) ----
  u32 aoff[4], alds[4];
#pragma unroll
  for (int i = 0; i < 4; ++i){
    int S = (w * 4 + i) * 64 + lane;          // A: 1024 chunks of 16B
    int L = S ^ ((S >> 3) & 7);
    int r = L >> 3, c = L & 7;
    int rr = row0 + r; if (rr > M - 1) rr = M - 1;   // tail clamp (rows >= M never written)
    aoff[i] = (u32)rr * (FF * 4u) + (u32)c * 16u;
    alds[i] = (u32)(w * 4 + i) * 1024u;
  }
  u32 boff[2], blds[2];
#pragma unroll
  for (int i = 0; i < 2; ++i){
    int S = (w * 2 + i) * 64 + lane;          // B: 512 chunks of 16B
    int L = S ^ ((S >> 3) & 7);
    int col = L >> 2, cb = L & 3;
    boff[i] = (u32)(col0 + col) * (FF * 2u) + (u32)cb * 16u;
    blds[i] = (u32)(w * 2 + i) * 1024u;
  }
  const char* Ab = (const char*)A;
  const char* Bb = (const char*)BT;

  f32x4 acc[4][4];
#pragma unroll
  for (int i = 0; i < 4; ++i)
#pragma unroll
    for (int j = 0; j < 4; ++j)
#pragma unroll
      for (int q = 0; q < 4; ++q) acc[i][j][q] = 0.f;

  // ---- prologue: stage tile 0 ----
#pragma unroll
  for (int i = 0; i < 4; ++i) gll16(Ab + aoff[i], (char*)&As[0][0] + alds[i]);
#pragma unroll
  for (int i = 0; i < 2; ++i) gll16(Bb + boff[i], (char*)&Bs[0][0] + blds[i]);
  asm volatile("s_waitcnt vmcnt(0)" ::: "memory");
  __builtin_amdgcn_s_barrier();

  for (int t = 0; t < FF / 32; ++t){
    const int cur = t & 1, nxt = cur ^ 1;
    // stage next tile (in flight across compute; drained at end-of-iter vmcnt)
    if (t < FF / 32 - 1){
      const int kb = (t + 1) * 32;
#pragma unroll
      for (int i = 0; i < 4; ++i) gll16(Ab + aoff[i] + kb * 4, (char*)&As[nxt][0] + alds[i]);
#pragma unroll
      for (int i = 0; i < 2; ++i) gll16(Bb + boff[i] + kb * 2, (char*)&Bs[nxt][0] + blds[i]);
    }
    // fragments from current buffer (swizzled ds_read)
    const char* Ac = (const char*)&As[cur][0];
    const char* Bc = (const char*)&Bs[cur][0];
    bf16x8 af[4], bfr[4];
#pragma unroll
    for (int nt = 0; nt < 4; ++nt){
      int col = wc + nt * 16 + lrow;
      int S = (col * 4 + g) ^ ((col >> 1) & 7);
      bfr[nt] = *(const bf16x8*)(Bc + S * 16);
    }
#pragma unroll
    for (int mt = 0; mt < 4; ++mt){
      int r = wr + mt * 16 + lrow;
      int S0 = r * 8 + ((2 * g)     ^ (r & 7));
      int S1 = r * 8 + ((2 * g + 1) ^ (r & 7));
      f32x4 fa = *(const f32x4*)(Ac + S0 * 16);
      f32x4 fb = *(const f32x4*)(Ac + S1 * 16);
      u32x4 q;
      q.x = cvtpk(fa[0], fa[1]);
      q.y = cvtpk(fa[2], fa[3]);
      q.z = cvtpk(fb[0], fb[1]);
      q.w = cvtpk(fb[2], fb[3]);
      af[mt] = __builtin_bit_cast(bf16x8, q);
    }
#pragma unroll
    for (int mt = 0; mt < 4; ++mt)
#pragma unroll
      for (int nt = 0; nt < 4; ++nt)
        acc[mt][nt] = __builtin_amdgcn_mfma_f32_16x16x32_bf16(af[mt], bfr[nt], acc[mt][nt], 0, 0, 0);
    // drain staged loads, flip buffers
    asm volatile("s_waitcnt vmcnt(0)" ::: "memory");
    __builtin_amdgcn_s_barrier();
  }

  const int orow = (lane >> 4) * 4, ocol = lane & 15;
#pragma unroll
  for (int mt = 0; mt < 4; ++mt)
#pragma unroll
    for (int i = 0; i < 4; ++i){
      int r = row0 + wr + mt * 16 + orow + i;
      if (r < M){
        u16* cp = C + (size_t)r * HH + col0 + wc + ocol;
#pragma unroll
        for (int nt = 0; nt < 4; ++nt)
          cp[nt * 16] = (u16)f2bf(acc[mt][nt][i]);
      }
    }
}

// ---------------- GCN CSR aggregate: H[d] = bias + xw[d]/(deg+1) + sum xw[s]*dis_s*dis_d ----------------
__global__ __launch_bounds__(256) void gcn_agg_k(
    const u16* __restrict__ XW, const int* __restrict__ rp,
    const int* __restrict__ deg, const int* __restrict__ csr,
    const float* __restrict__ bias, u16* __restrict__ H, int n)
{
  const int d = blockIdx.x * 4 + (threadIdx.x >> 6);
  if (d >= n) return;
  const int lane = threadIdx.x & 63;
  const int dg = deg[d];
  const float disd = rsqrtf((float)dg + 1.0f);
  const uint2* xw2 = (const uint2*)XW;
  uint2 sv = xw2[(size_t)d * 64 + lane];
  const float sw = disd * disd;
  float a0 = bflo(sv.x) * sw, a1 = bfhi(sv.x) * sw;
  float a2 = bflo(sv.y) * sw, a3 = bfhi(sv.y) * sw;
  const int s0 = rp[d], s1 = s0 + dg;
  for (int i = s0; i < s1; ++i){
    int s = csr[i];
    float wgt = rsqrtf((float)deg[s] + 1.0f) * disd;
    uint2 v = xw2[(size_t)s * 64 + lane];
    a0 = fmaf(bflo(v.x), wgt, a0); a1 = fmaf(bfhi(v.x), wgt, a1);
    a2 = fmaf(bflo(v.y), wgt, a2); a3 = fmaf(bfhi(v.y), wgt, a3);
  }
  const float4 bv = *(const float4*)(bias + lane * 4);
  a0 += bv.x; a1 += bv.y; a2 += bv.z; a3 += bv.w;
  uint2 o; o.x = pack2(a0, a1); o.y = pack2(a2, a3);
  ((uint2*)H)[(size_t)d * 64 + lane] = o;
}

// ---------------- SAGE CSR mean aggregate: M[d] = (sum X[s]) / max(deg,1) ----------------
__global__ __launch_bounds__(256) void sage_mean_k(
    const u16* __restrict__ X, const int* __restrict__ rp,
    const int* __restrict__ deg, const int* __restrict__ csr,
    u16* __restrict__ Mo, int n)
{
  const int d = blockIdx.x * 4 + (threadIdx.x >> 6);
  if (d >= n) return;
  const int lane = threadIdx.x & 63;
  const int dg = deg[d];
  const uint2* x2 = (const uint2*)X;
  float a0 = 0.f, a1 = 0.f, a2 = 0.f, a3 = 0.f;
  const int s0 = rp[d], s1 = s0 + dg;
  for (int i = s0; i < s1; ++i){
    int s = csr[i];
    uint2 v = x2[(size_t)s * 64 + lane];
    a0 += bflo(v.x); a1 += bfhi(v.x);
    a2 += bflo(v.y); a3 += bfhi(v.y);
  }
  const float sc = 1.0f / (float)(dg > 0 ? dg : 1);
  uint2 o; o.x = pack2(a0 * sc, a1 * sc); o.y = pack2(a2 * sc, a3 * sc);
  ((uint2*)Mo)[(size_t)d * 64 + lane] = o;
}

// ---------------- combine: X0 = relu(h)+relu(g); G1 = relu(g)+g (bf16 pairs) ----------------
__global__ void combine_k(u32* __restrict__ X0, u32* __restrict__ G1,
                          const u32* __restrict__ H1, const u32* __restrict__ H2)
{
  int i = blockIdx.x * 256 + threadIdx.x;
  u32 uh = H1[i], ug = H2[i];
  float h0 = bflo(uh), h1 = bfhi(uh), g0 = bflo(ug), g1 = bfhi(ug);
  float rh0 = fmaxf(h0, 0.f), rh1 = fmaxf(h1, 0.f);
  float rg0 = fmaxf(g0, 0.f), rg1 = fmaxf(g1, 0.f);
  X0[i] = pack2(rh0 + rg0, rh1 + rg1);
  G1[i] = pack2(rg0 + g0, rg1 + g1);
}

// ---------------- SAGE MFMA GEMM: S = relu(A1@B1 + A2@B2 + bias), all bf16, N=128 ----------------
__global__ __launch_bounds__(256) void sage_gemm_k(
    const u16* __restrict__ A1, const u16* __restrict__ A2,
    const u16* __restrict__ B1T, const u16* __restrict__ B2T,
    const float* __restrict__ bias, u16* __restrict__ S, int M)
{
  __shared__ u16 As[128][40];
  __shared__ u16 Bs[128][40];
  const int tid = threadIdx.x;
  const int w = tid >> 6, lane = tid & 63;
  const int row0 = blockIdx.x * 128;
  const int wr = (w >> 1) * 64, wc = (w & 1) * 64;
  const int lrow = lane & 15, lk = (lane >> 4) * 8;
  f32x4 acc[4][4];
#pragma unroll
  for (int i = 0; i < 4; ++i)
#pragma unroll
    for (int j = 0; j < 4; ++j)
#pragma unroll
      for (int q = 0; q < 4; ++q) acc[i][j][q] = 0.f;

  for (int pass = 0; pass < 2; ++pass){
    const u16* Ap = pass ? A2 : A1;
    const u16* Bp = pass ? B2T : B1T;
    for (int kb = 0; kb < HH; kb += 32){
      for (int c = tid; c < 512; c += 256){
        int r = c >> 2, part = c & 3;
        int grow = row0 + r;
        uint4 v = make_uint4(0,0,0,0);
        if (grow < M) v = *(const uint4*)(Ap + (size_t)grow * HH + kb + part * 8);
        *(uint4*)&As[r][part * 8] = v;
      }
      for (int c = tid; c < 512; c += 256){
        int n = c >> 2, part = c & 3;
        uint4 v = *(const uint4*)(Bp + (size_t)n * HH + kb + part * 8);
        *(uint4*)&Bs[n][part * 8] = v;
      }
      __syncthreads();
      bf16x8 af[4], bfr[4];
#pragma unroll
      for (int mt = 0; mt < 4; ++mt) af[mt]  = *(const bf16x8*)&As[wr + mt*16 + lrow][lk];
#pragma unroll
      for (int nt = 0; nt < 4; ++nt) bfr[nt] = *(const bf16x8*)&Bs[wc + nt*16 + lrow][lk];
#pragma unroll
      for (int mt = 0; mt < 4; ++mt)
#pragma unroll
        for (int nt = 0; nt < 4; ++nt)
          acc[mt][nt] = __builtin_amdgcn_mfma_f32_16x16x32_bf16(af[mt], bfr[nt], acc[mt][nt], 0, 0, 0);
      __syncthreads();
    }
  }
  const int orow = (lane >> 4) * 4, ocol = lane & 15;
#pragma unroll
  for (int mt = 0; mt < 4; ++mt)
#pragma unroll
    for (int i = 0; i < 4; ++i){
      int r = row0 + wr + mt*16 + orow + i;
      if (r < M){
        u16* cp = S + (size_t)r * HD2 + wc + ocol;
#pragma unroll
        for (int nt = 0; nt < 4; ++nt){
          float v = acc[mt][nt][i] + bias[wc + nt*16 + ocol];
          cp[nt * 16] = (u16)f2bf(fmaxf(v, 0.f));
        }
      }
    }
}

// ---------------- fused MLP (MFMA) + LayerNorm + dot(Wm2) -> per-block f64 partial ----------------
__global__ __launch_bounds__(256) void mlp_mfma_k(
    const u16* __restrict__ Xin,       // [M][128] bf16 rows
    const u16* __restrict__ W1T,       // [128][128] bf16: W1T[j*128+k] = Wm1[k][j]
    const float* __restrict__ bm1,
    const float* __restrict__ lnw, const float* __restrict__ lnb,
    const float* __restrict__ Wm2, const float* __restrict__ bm2,
    double* __restrict__ partial, int M)
{
  __shared__ u16 Wsh[HD2][136];        // pad row to 272B: 2-way bank alias only (free)
  __shared__ double wsum[4];
  const int tid = threadIdx.x;
  const int lane = tid & 63, wv = tid >> 6;
  const int g = lane >> 4, cn = lane & 15;

  for (int i = tid; i < HD2 * 16; i += 256){
    int j = i >> 4, c = i & 15;
    *(uint4*)&Wsh[j][c * 8] = ((const uint4*)W1T)[i];
  }

  f32x4 b1v[8], c1v[8];
  float S1 = 0.f, C0 = 0.f;
#pragma unroll
  for (int jt = 0; jt < 8; ++jt){
    int j = jt * 16 + g * 4;
    float4 bb = *(const float4*)&bm1[j];
    float4 lw = *(const float4*)&lnw[j];
    float4 lb = *(const float4*)&lnb[j];
    float4 w2 = *(const float4*)&Wm2[j];
    b1v[jt][0] = bb.x; b1v[jt][1] = bb.y; b1v[jt][2] = bb.z; b1v[jt][3] = bb.w;
    c1v[jt][0] = lw.x * w2.x; c1v[jt][1] = lw.y * w2.y;
    c1v[jt][2] = lw.z * w2.z; c1v[jt][3] = lw.w * w2.w;
    S1 += c1v[jt][0] + c1v[jt][1] + c1v[jt][2] + c1v[jt][3];
    C0 += lb.x * w2.x + lb.y * w2.y + lb.z * w2.z + lb.w * w2.w;
  }
  S1 += __shfl_xor(S1, 16); S1 += __shfl_xor(S1, 32);
  C0 += __shfl_xor(C0, 16); C0 += __shfl_xor(C0, 32);
  const float bm2v = bm2[0];
  __syncthreads();

  double local = 0.0;
  const int stride = gridDim.x * 64;
  for (int base = blockIdx.x * 64 + wv * 16; base < M; base += stride){
    const int node = base + cn;
    const bool nv = node < M;
    f32x4 acc[8];
#pragma unroll
    for (int jt = 0; jt < 8; ++jt){ acc[jt][0]=0.f; acc[jt][1]=0.f; acc[jt][2]=0.f; acc[jt][3]=0.f; }
#pragma unroll
    for (int ks = 0; ks < 4; ++ks){
      bf16x8 bfv = {0,0,0,0,0,0,0,0};
      if (nv) bfv = *(const bf16x8*)(Xin + (size_t)node * HD2 + ks * 32 + g * 8);
#pragma unroll
      for (int jt = 0; jt < 8; ++jt){
        bf16x8 afr = *(const bf16x8*)&Wsh[jt * 16 + cn][ks * 32 + g * 8];
        acc[jt] = __builtin_amdgcn_mfma_f32_16x16x32_bf16(afr, bfv, acc[jt], 0, 0, 0);
      }
    }
    float s = 0.f;
#pragma unroll
    for (int jt = 0; jt < 8; ++jt){
#pragma unroll
      for (int r = 0; r < 4; ++r){
        acc[jt][r] += b1v[jt][r];
        s += acc[jt][r];
      }
    }
    s += __shfl_xor(s, 16); s += __shfl_xor(s, 32);
    const float mu = s * (1.0f / HD2);
    float vs = 0.f, d1 = 0.f;
#pragma unroll
    for (int jt = 0; jt < 8; ++jt){
#pragma unroll
      for (int r = 0; r < 4; ++r){
        float dv = acc[jt][r] - mu;
        vs = fmaf(dv, dv, vs);
        d1 = fmaf(acc[jt][r], c1v[jt][r], d1);
      }
    }
    vs += __shfl_xor(vs, 16); vs += __shfl_xor(vs, 32);
    d1 += __shfl_xor(d1, 16); d1 += __shfl_xor(d1, 32);
    const float rs = rsqrtf(vs * (1.0f / HD2) + 1e-5f);
    const float p = rs * (d1 - mu * S1) + C0 + bm2v;
    if (nv && g == 0) local += (double)p;
  }
#pragma unroll
  for (int off = 32; off > 0; off >>= 1) local += __shfl_xor(local, off);
  if (lane == 0) wsum[wv] = local;
  __syncthreads();
  if (tid == 0) partial[blockIdx.x] = wsum[0] + wsum[1] + wsum[2] + wsum[3];
}

// ---------------- final: sum 1024 f64 partials, dtype-robust output word ----------------
__global__ __launch_bounds__(256) void final_reduce_k(
    const double* __restrict__ P, u32* __restrict__ out)
{
  __shared__ double sm[256];
  const int tid = threadIdx.x;
  double s = P[tid] + P[tid + 256] + P[tid + 512] + P[tid + 768];
  sm[tid] = s;
  __syncthreads();
  for (int h = 128; h > 0; h >>= 1){
    if (tid < h) sm[tid] += sm[tid + h];
    __syncthreads();
  }
  if (tid == 0){
    float v = (float)(sm[0] * (1.0 / (2.0 * (double)NN)));
    u32 bf = f2bf(v);
    out[0] = (bf << 16) | bf;   // fp32 reader ~v; bf16 reader low half exact
  }
}

extern "C" void kernel_launch(void* const* d_in, const int* in_sizes, int n_in,
                              void* d_out, int out_size, void* d_ws, size_t ws_size,
                              hipStream_t stream)
{
  const float* x   = (const float*)d_in[0];
  const float* x1  = (const float*)d_in[1];
  const int* ei  = (const int*)d_in[2];
  const int* ei1 = (const int*)d_in[3];
  const float* Wg1 = (const float*)d_in[4];
  const float* bg1 = (const float*)d_in[5];
  const float* Wg2 = (const float*)d_in[6];
  const float* bg2 = (const float*)d_in[7];
  const float* Wl1 = (const float*)d_in[8];
  const float* bl1 = (const float*)d_in[9];
  const float* Wr1 = (const float*)d_in[10];
  const float* Wl2 = (const float*)d_in[11];
  const float* bl2 = (const float*)d_in[12];
  const float* Wr2 = (const float*)d_in[13];
  const float* Wm1 = (const float*)d_in[14];
  const float* bm1 = (const float*)d_in[15];
  const float* lnw = (const float*)d_in[16];
  const float* lnb = (const float*)d_in[17];
  const float* Wm2 = (const float*)d_in[18];
  const float* bm2 = (const float*)d_in[19];

  const int* src1 = ei,  * dst1 = ei + EE;
  const int* src2 = ei1, * dst2 = ei1 + EE;

  // ---- workspace layout (bf16 node features + CSR + partials), ~264 MB ----
  u16* U0 = (u16*)d_ws;                        // XW1 -> X0     [NN*HH]
  u16* U1 = U0 + (size_t)NN * HH;              // XW2 -> G1
  u16* U2 = U1 + (size_t)NN * HH;              // H1  -> M1
  u16* U3 = U2 + (size_t)NN * HH;              // H2  -> M2
  u16* U4 = U3 + (size_t)NN * HH;              // S1 [NN*HD2]
  u16* U5 = U4 + (size_t)NN * HD2;             // S2 (contiguous after S1)
  u16* WG1T = U5 + (size_t)NN * HD2;           // [HH][FF]
  u16* WG2T = WG1T + HH * FF;
  u16* WL1T = WG2T + HH * FF;                  // [HD2][HH]
  u16* WR1T = WL1T + HD2 * HH;
  u16* WL2T = WR1T + HD2 * HH;
  u16* WR2T = WL2T + HD2 * HH;
  int* deg1 = (int*)(WR2T + HD2 * HH);
  int* deg2 = deg1 + NN;
  int* fill1 = deg2 + NN;
  int* fill2 = fill1 + NN;
  int* rp1 = fill2 + NN;
  int* rp2 = rp1 + NN;
  int* aux1 = rp2 + NN;
  int* aux2 = aux1 + 128;
  int* csr1 = aux2 + 128;
  int* csr2 = csr1 + EE;
  double* P = (double*)(csr2 + EE);            // 1024 doubles (8B-aligned)
  u16* WM1T = U0;                              // reuse U0 after sage GEMMs (stream-serial)

  const int eblk = (EE + 255) / 256;
  const int nchunks = (NN + 1023) / 1024;      // 98

  // ---- CSR build (both graphs) ----
  zero_int_k<<<512, 256, 0, stream>>>(deg1, 4 * NN);   // deg1,deg2,fill1,fill2
  count_deg_k<<<eblk, 256, 0, stream>>>(dst1, deg1, EE);
  count_deg_k<<<eblk, 256, 0, stream>>>(dst2, deg2, EE);
  scan1_k<<<nchunks, 256, 0, stream>>>(deg1, rp1, aux1, NN);
  scan1_k<<<nchunks, 256, 0, stream>>>(deg2, rp2, aux2, NN);
  scan2_k<<<1, 64, 0, stream>>>(aux1, nchunks);
  scan2_k<<<1, 64, 0, stream>>>(aux2, nchunks);
  scan3_k<<<(NN + 255) / 256, 256, 0, stream>>>(rp1, aux1, NN);
  scan3_k<<<(NN + 255) / 256, 256, 0, stream>>>(rp2, aux2, NN);
  csr_fill_k<<<eblk, 256, 0, stream>>>(src1, dst1, rp1, fill1, csr1, EE);
  csr_fill_k<<<eblk, 256, 0, stream>>>(src2, dst2, rp2, fill2, csr2, EE);

  // ---- weight convert+transpose ----
  wtcvt_k<<<512, 256, 0, stream>>>(Wg1, WG1T, FF, HH - 1, 8, FF * HH);
  wtcvt_k<<<512, 256, 0, stream>>>(Wg2, WG2T, FF, HH - 1, 8, FF * HH);
  wtcvt_k<<<128, 256, 0, stream>>>(Wl1, WL1T, HH, HD2 - 1, 7, HH * HD2);
  wtcvt_k<<<128, 256, 0, stream>>>(Wr1, WR1T, HH, HD2 - 1, 7, HH * HD2);
  wtcvt_k<<<128, 256, 0, stream>>>(Wl2, WL2T, HH, HD2 - 1, 7, HH * HD2);
  wtcvt_k<<<128, 256, 0, stream>>>(Wr2, WR2T, HH, HD2 - 1, 7, HH * HD2);

  // ---- GCN linear (MFMA, 2-phase pipelined) ----
  dim3 ggrid((NN + 127) / 128, HH / 128);      // (782, 2)
  gemm_xw_k<<<ggrid, 256, 0, stream>>>(x,  WG1T, U0, NN);
  gemm_xw_k<<<ggrid, 256, 0, stream>>>(x1, WG2T, U1, NN);

  // ---- GCN aggregate (CSR gather, fused self-loop + bias) ----
  gcn_agg_k<<<NN / 4, 256, 0, stream>>>(U0, rp1, deg1, csr1, bg1, U2, NN);
  gcn_agg_k<<<NN / 4, 256, 0, stream>>>(U1, rp2, deg2, csr2, bg2, U3, NN);

  // ---- combine ----
  combine_k<<<NN * HH / 512, 256, 0, stream>>>((u32*)U0, (u32*)U1, (const u32*)U2, (const u32*)U3);

  // ---- SAGE mean aggregate (CSR gather, fused mean) ----
  sage_mean_k<<<NN / 4, 256, 0, stream>>>(U0, rp1, deg1, csr1, U2, NN);
  sage_mean_k<<<NN / 4, 256, 0, stream>>>(U1, rp2, deg2, csr2, U3, NN);

  // ---- SAGE linear (MFMA, two K-passes) + relu ----
  sage_gemm_k<<<(NN + 127) / 128, 256, 0, stream>>>(U2, U0, WL1T, WR1T, bl1, U4, NN);
  sage_gemm_k<<<(NN + 127) / 128, 256, 0, stream>>>(U3, U1, WL2T, WR2T, bl2, U5, NN);

  // ---- Wm1^T bf16 (into U0, free after the sage GEMMs) ----
  wtcvt_k<<<64, 256, 0, stream>>>(Wm1, WM1T, HD2, HD2 - 1, 7, HD2 * HD2);

  // ---- fused MLP + LN + reduce over both halves (U4||U5 contiguous, M = 2N) ----
  mlp_mfma_k<<<1024, 256, 0, stream>>>(U4, WM1T, bm1, lnw, lnb, Wm2, bm2, P, 2 * NN);

  final_reduce_k<<<1, 256, 0, stream>>>(P, (u32*)d_out);
}

// Round 3
// 1230.984 us; speedup vs baseline: 1.2439x; 1.0026x over previous
//
#include <hip/hip_runtime.h>

#define NN 100000
#define EE 600000
#define FF 512
#define HH 256
#define HD2 128

typedef unsigned short u16;
typedef unsigned int u32;
typedef __attribute__((ext_vector_type(4))) float f32x4;
typedef __attribute__((ext_vector_type(8))) short bf16x8;
typedef __attribute__((ext_vector_type(4))) unsigned int u32x4;

__device__ __forceinline__ float bflo(u32 u){ return __uint_as_float(u << 16); }
__device__ __forceinline__ float bfhi(u32 u){ return __uint_as_float(u & 0xffff0000u); }
__device__ __forceinline__ u32 f2bf(float x){
  u32 u = __float_as_uint(x);
  return (u + 0x7FFFu + ((u >> 16) & 1u)) >> 16;
}
__device__ __forceinline__ u32 pack2(float x, float y){ return f2bf(x) | (f2bf(y) << 16); }

// async global->LDS, 16B per lane, linear dest (wave-uniform base + lane*16)
__device__ __forceinline__ void gll16(const void* g, void* l){
  __builtin_amdgcn_global_load_lds((const __attribute__((address_space(1))) void*)g,
                                   (__attribute__((address_space(3))) void*)l, 16, 0, 0);
}
// packed f32x2 -> bf16x2 (RNE), CDNA4; no builtin exists (T12)
__device__ __forceinline__ u32 cvtpk(float lo, float hi){
  u32 r;
  asm("v_cvt_pk_bf16_f32 %0, %1, %2" : "=v"(r) : "v"(lo), "v"(hi));
  return r;
}

// ---------------- utility: zero ints ----------------
__global__ void zero_int_k(int* __restrict__ p, int n){
  int i = blockIdx.x * 256 + threadIdx.x;
  int st = gridDim.x * 256;
  for (; i < n; i += st) p[i] = 0;
}

// ---------------- degree count (int) ----------------
__global__ void count_deg_k(const int* __restrict__ dst, int* __restrict__ deg, int nE){
  int e = blockIdx.x * 256 + threadIdx.x;
  if (e < nE) atomicAdd(&deg[dst[e]], 1);
}

// ---------------- exclusive scan (1024 elems / block) ----------------
__global__ __launch_bounds__(256) void scan1_k(const int* __restrict__ deg, int* __restrict__ out,
                                               int* __restrict__ aux, int n){
  __shared__ int sm[256];
  const int t = threadIdx.x;
  const int base = blockIdx.x * 1024 + t * 4;
  int v0 = (base+0) < n ? deg[base+0] : 0;
  int v1 = (base+1) < n ? deg[base+1] : 0;
  int v2 = (base+2) < n ? deg[base+2] : 0;
  int v3 = (base+3) < n ? deg[base+3] : 0;
  int s = v0 + v1 + v2 + v3;
  sm[t] = s;
  __syncthreads();
  for (int off = 1; off < 256; off <<= 1){
    int x = (t >= off) ? sm[t - off] : 0;
    __syncthreads();
    sm[t] += x;
    __syncthreads();
  }
  if (t == 255) aux[blockIdx.x] = sm[255];
  int run = sm[t] - s;             // exclusive prefix within chunk
  if (base+0 < n) out[base+0] = run;            run += v0;
  if (base+1 < n) out[base+1] = run;            run += v1;
  if (base+2 < n) out[base+2] = run;            run += v2;
  if (base+3 < n) out[base+3] = run;
}
__global__ void scan2_k(int* __restrict__ aux, int nchunks){
  if (threadIdx.x == 0){
    int run = 0;
    for (int i = 0; i < nchunks; ++i){ int t = aux[i]; aux[i] = run; run += t; }
  }
}
__global__ void scan3_k(int* __restrict__ out, const int* __restrict__ aux, int n){
  int i = blockIdx.x * 256 + threadIdx.x;
  if (i < n) out[i] += aux[i >> 10];
}

// ---------------- CSR fill: csr[pos] = src of each edge, grouped by dst ----------------
__global__ void csr_fill_k(const int* __restrict__ src, const int* __restrict__ dst,
                           const int* __restrict__ rp, int* __restrict__ fill,
                           int* __restrict__ csr, int nE){
  int e = blockIdx.x * 256 + threadIdx.x;
  if (e >= nE) return;
  int d = dst[e];
  int pos = rp[d] + atomicAdd(&fill[d], 1);
  csr[pos] = src[e];
}

// ---------------- weight convert + transpose: W[k][n] f32 -> WT[n][k] bf16 ----------------
__global__ void wtcvt_k(const float* __restrict__ W, u16* __restrict__ WT,
                        int K, int nmask, int nshift, int total){
  int idx = blockIdx.x * 256 + threadIdx.x;
  if (idx >= total) return;
  int k = idx >> nshift, n = idx & nmask;
  WT[(size_t)n * K + k] = (u16)f2bf(W[idx]);
}

// ---------------- MFMA GEMM: C_bf16[M,256] = A_f32[M,512] @ B (BT bf16 [256][512]) ----------
// Depth-2 pipelined global_load_lds (T3+T4): 3 LDS buffer sets, prefetch t+1 and t+2,
// counted s_waitcnt vmcnt(6) per iter (never 0 in steady state) -- loads get ~2 compute
// phases to land, covering ~900cy HBM latency. 16B-chunk XOR swizzle (T2, rule#21):
// storage chunk S = L ^ ((L>>3)&7) (involution); inverse-swizzled global source + swizzled
// ds_read, linear gll dest. A stays f32 in LDS; f32->bf16 via v_cvt_pk_bf16_f32 at use.
__global__ __launch_bounds__(256) void gemm_xw_k(
    const float* __restrict__ A, const u16* __restrict__ BT,
    u16* __restrict__ C, int M)
{
  __shared__ float As[3][4096];   // 48 KB: per buf [128 rows][32 k] f32, swizzled chunks
  __shared__ u16  Bs[3][4096];    // 24 KB: per buf [128 cols][32 k] bf16, swizzled chunks
  const int tid = threadIdx.x;
  const int w = tid >> 6, lane = tid & 63;
  const int row0 = blockIdx.x * 128, col0 = blockIdx.y * 128;
  const int wr = (w >> 1) * 64, wc = (w & 1) * 64;
  const int lrow = lane & 15, g = lane >> 4;   // fragment row, k-group

  // ---- staging descriptors (per-lane global byte offsets; LDS dests wave-uniform) ----
  u32 aoff[4], alds[4];
#pragma unroll
  for (int i = 0; i < 4; ++i){
    int S = (w * 4 + i) * 64 + lane;          // A: 1024 chunks of 16B
    int L = S ^ ((S >> 3) & 7);
    int r = L >> 3, c = L & 7;
    int rr = row0 + r; if (rr > M - 1) rr = M - 1;   // tail clamp (rows >= M never stored)
    aoff[i] = (u32)rr * (FF * 4u) + (u32)c * 16u;
    alds[i] = (u32)(w * 4 + i) * 1024u;
  }
  u32 boff[2], blds[2];
#pragma unroll
  for (int i = 0; i < 2; ++i){
    int S = (w * 2 + i) * 64 + lane;          // B: 512 chunks of 16B
    int L = S ^ ((S >> 3) & 7);
    int col = L >> 2, cb = L & 3;
    boff[i] = (u32)(col0 + col) * (FF * 2u) + (u32)cb * 16u;
    blds[i] = (u32)(w * 2 + i) * 1024u;
  }
  const char* Ab = (const char*)A;
  const char* Bb = (const char*)BT;

  f32x4 acc[4][4];
#pragma unroll
  for (int i = 0; i < 4; ++i)
#pragma unroll
    for (int j = 0; j < 4; ++j)
#pragma unroll
      for (int q = 0; q < 4; ++q) acc[i][j][q] = 0.f;

  // stage tile tt into buffer buf (6 global_load_lds per wave)
  auto STAGE = [&](int tt, int buf){
    const int kb = tt * 32;
    char* ab = (char*)&As[buf][0];
    char* bb = (char*)&Bs[buf][0];
#pragma unroll
    for (int i = 0; i < 4; ++i) gll16(Ab + aoff[i] + kb * 4, ab + alds[i]);
#pragma unroll
    for (int i = 0; i < 2; ++i) gll16(Bb + boff[i] + kb * 2, bb + blds[i]);
  };

  // ---- prologue: prefetch tiles 0 and 1 (12 loads in flight) ----
  STAGE(0, 0);
  STAGE(1, 1);
  asm volatile("s_waitcnt vmcnt(6)" ::: "memory");   // tile 0 landed; tile 1 in flight
  __builtin_amdgcn_s_barrier();

  int cur = 0, n1 = 1, n2 = 2;
  for (int t = 0; t < FF / 32; ++t){
    // issue prefetch of tile t+2 first (max lead time over its consumption)
    if (t + 2 < FF / 32) STAGE(t + 2, n2);

    // fragments from current buffer (swizzled ds_read)
    const char* Ac = (const char*)&As[cur][0];
    const char* Bc = (const char*)&Bs[cur][0];
    bf16x8 af[4], bfr[4];
#pragma unroll
    for (int nt = 0; nt < 4; ++nt){
      int col = wc + nt * 16 + lrow;
      int S = (col * 4 + g) ^ ((col >> 1) & 7);
      bfr[nt] = *(const bf16x8*)(Bc + S * 16);
    }
#pragma unroll
    for (int mt = 0; mt < 4; ++mt){
      int r = wr + mt * 16 + lrow;
      int S0 = r * 8 + ((2 * g)     ^ (r & 7));
      int S1 = r * 8 + ((2 * g + 1) ^ (r & 7));
      f32x4 fa = *(const f32x4*)(Ac + S0 * 16);
      f32x4 fb = *(const f32x4*)(Ac + S1 * 16);
      u32x4 q;
      q.x = cvtpk(fa[0], fa[1]);
      q.y = cvtpk(fa[2], fa[3]);
      q.z = cvtpk(fb[0], fb[1]);
      q.w = cvtpk(fb[2], fb[3]);
      af[mt] = __builtin_bit_cast(bf16x8, q);
    }
#pragma unroll
    for (int mt = 0; mt < 4; ++mt)
#pragma unroll
      for (int nt = 0; nt < 4; ++nt)
        acc[mt][nt] = __builtin_amdgcn_mfma_f32_16x16x32_bf16(af[mt], bfr[nt], acc[mt][nt], 0, 0, 0);

    // release: ensure NEXT tile is resident (counted wait; 0 only at pipeline drain),
    // barrier also protects buf[cur] from being restaged (t+3) before all waves read it.
    if (t < FF / 32 - 1){
      if (t + 2 < FF / 32) asm volatile("s_waitcnt vmcnt(6)" ::: "memory");
      else                 asm volatile("s_waitcnt vmcnt(0)" ::: "memory");
      __builtin_amdgcn_s_barrier();
    }
    int tmp = cur; cur = n1; n1 = n2; n2 = tmp;
  }

  const int orow = (lane >> 4) * 4, ocol = lane & 15;
#pragma unroll
  for (int mt = 0; mt < 4; ++mt)
#pragma unroll
    for (int i = 0; i < 4; ++i){
      int r = row0 + wr + mt * 16 + orow + i;
      if (r < M){
        u16* cp = C + (size_t)r * HH + col0 + wc + ocol;
#pragma unroll
        for (int nt = 0; nt < 4; ++nt)
          cp[nt * 16] = (u16)f2bf(acc[mt][nt][i]);
      }
    }
}

// ---------------- GCN CSR aggregate: H[d] = bias + xw[d]/(deg+1) + sum xw[s]*dis_s*dis_d ----------------
__global__ __launch_bounds__(256) void gcn_agg_k(
    const u16* __restrict__ XW, const int* __restrict__ rp,
    const int* __restrict__ deg, const int* __restrict__ csr,
    const float* __restrict__ bias, u16* __restrict__ H, int n)
{
  const int d = blockIdx.x * 4 + (threadIdx.x >> 6);
  if (d >= n) return;
  const int lane = threadIdx.x & 63;
  const int dg = deg[d];
  const float disd = rsqrtf((float)dg + 1.0f);
  const uint2* xw2 = (const uint2*)XW;
  uint2 sv = xw2[(size_t)d * 64 + lane];
  const float sw = disd * disd;
  float a0 = bflo(sv.x) * sw, a1 = bfhi(sv.x) * sw;
  float a2 = bflo(sv.y) * sw, a3 = bfhi(sv.y) * sw;
  const int s0 = rp[d], s1 = s0 + dg;
  for (int i = s0; i < s1; ++i){
    int s = csr[i];
    float wgt = rsqrtf((float)deg[s] + 1.0f) * disd;
    uint2 v = xw2[(size_t)s * 64 + lane];
    a0 = fmaf(bflo(v.x), wgt, a0); a1 = fmaf(bfhi(v.x), wgt, a1);
    a2 = fmaf(bflo(v.y), wgt, a2); a3 = fmaf(bfhi(v.y), wgt, a3);
  }
  const float4 bv = *(const float4*)(bias + lane * 4);
  a0 += bv.x; a1 += bv.y; a2 += bv.z; a3 += bv.w;
  uint2 o; o.x = pack2(a0, a1); o.y = pack2(a2, a3);
  ((uint2*)H)[(size_t)d * 64 + lane] = o;
}

// ---------------- SAGE CSR mean aggregate: M[d] = (sum X[s]) / max(deg,1) ----------------
__global__ __launch_bounds__(256) void sage_mean_k(
    const u16* __restrict__ X, const int* __restrict__ rp,
    const int* __restrict__ deg, const int* __restrict__ csr,
    u16* __restrict__ Mo, int n)
{
  const int d = blockIdx.x * 4 + (threadIdx.x >> 6);
  if (d >= n) return;
  const int lane = threadIdx.x & 63;
  const int dg = deg[d];
  const uint2* x2 = (const uint2*)X;
  float a0 = 0.f, a1 = 0.f, a2 = 0.f, a3 = 0.f;
  const int s0 = rp[d], s1 = s0 + dg;
  for (int i = s0; i < s1; ++i){
    int s = csr[i];
    uint2 v = x2[(size_t)s * 64 + lane];
    a0 += bflo(v.x); a1 += bfhi(v.x);
    a2 += bflo(v.y); a3 += bfhi(v.y);
  }
  const float sc = 1.0f / (float)(dg > 0 ? dg : 1);
  uint2 o; o.x = pack2(a0 * sc, a1 * sc); o.y = pack2(a2 * sc, a3 * sc);
  ((uint2*)Mo)[(size_t)d * 64 + lane] = o;
}

// ---------------- combine: X0 = relu(h)+relu(g); G1 = relu(g)+g (bf16 pairs) ----------------
__global__ void combine_k(u32* __restrict__ X0, u32* __restrict__ G1,
                          const u32* __restrict__ H1, const u32* __restrict__ H2)
{
  int i = blockIdx.x * 256 + threadIdx.x;
  u32 uh = H1[i], ug = H2[i];
  float h0 = bflo(uh), h1 = bfhi(uh), g0 = bflo(ug), g1 = bfhi(ug);
  float rh0 = fmaxf(h0, 0.f), rh1 = fmaxf(h1, 0.f);
  float rg0 = fmaxf(g0, 0.f), rg1 = fmaxf(g1, 0.f);
  X0[i] = pack2(rh0 + rg0, rh1 + rg1);
  G1[i] = pack2(rg0 + g0, rg1 + g1);
}

// ---------------- SAGE MFMA GEMM: S = relu(A1@B1 + A2@B2 + bias), all bf16, N=128 ----------------
__global__ __launch_bounds__(256) void sage_gemm_k(
    const u16* __restrict__ A1, const u16* __restrict__ A2,
    const u16* __restrict__ B1T, const u16* __restrict__ B2T,
    const float* __restrict__ bias, u16* __restrict__ S, int M)
{
  __shared__ u16 As[128][40];
  __shared__ u16 Bs[128][40];
  const int tid = threadIdx.x;
  const int w = tid >> 6, lane = tid & 63;
  const int row0 = blockIdx.x * 128;
  const int wr = (w >> 1) * 64, wc = (w & 1) * 64;
  const int lrow = lane & 15, lk = (lane >> 4) * 8;
  f32x4 acc[4][4];
#pragma unroll
  for (int i = 0; i < 4; ++i)
#pragma unroll
    for (int j = 0; j < 4; ++j)
#pragma unroll
      for (int q = 0; q < 4; ++q) acc[i][j][q] = 0.f;

  for (int pass = 0; pass < 2; ++pass){
    const u16* Ap = pass ? A2 : A1;
    const u16* Bp = pass ? B2T : B1T;
    for (int kb = 0; kb < HH; kb += 32){
      for (int c = tid; c < 512; c += 256){
        int r = c >> 2, part = c & 3;
        int grow = row0 + r;
        uint4 v = make_uint4(0,0,0,0);
        if (grow < M) v = *(const uint4*)(Ap + (size_t)grow * HH + kb + part * 8);
        *(uint4*)&As[r][part * 8] = v;
      }
      for (int c = tid; c < 512; c += 256){
        int n = c >> 2, part = c & 3;
        uint4 v = *(const uint4*)(Bp + (size_t)n * HH + kb + part * 8);
        *(uint4*)&Bs[n][part * 8] = v;
      }
      __syncthreads();
      bf16x8 af[4], bfr[4];
#pragma unroll
      for (int mt = 0; mt < 4; ++mt) af[mt]  = *(const bf16x8*)&As[wr + mt*16 + lrow][lk];
#pragma unroll
      for (int nt = 0; nt < 4; ++nt) bfr[nt] = *(const bf16x8*)&Bs[wc + nt*16 + lrow][lk];
#pragma unroll
      for (int mt = 0; mt < 4; ++mt)
#pragma unroll
        for (int nt = 0; nt < 4; ++nt)
          acc[mt][nt] = __builtin_amdgcn_mfma_f32_16x16x32_bf16(af[mt], bfr[nt], acc[mt][nt], 0, 0, 0);
      __syncthreads();
    }
  }
  const int orow = (lane >> 4) * 4, ocol = lane & 15;
#pragma unroll
  for (int mt = 0; mt < 4; ++mt)
#pragma unroll
    for (int i = 0; i < 4; ++i){
      int r = row0 + wr + mt*16 + orow + i;
      if (r < M){
        u16* cp = S + (size_t)r * HD2 + wc + ocol;
#pragma unroll
        for (int nt = 0; nt < 4; ++nt){
          float v = acc[mt][nt][i] + bias[wc + nt*16 + ocol];
          cp[nt * 16] = (u16)f2bf(fmaxf(v, 0.f));
        }
      }
    }
}

// ---------------- fused MLP (MFMA) + LayerNorm + dot(Wm2) -> per-block f64 partial ----------------
__global__ __launch_bounds__(256) void mlp_mfma_k(
    const u16* __restrict__ Xin,       // [M][128] bf16 rows
    const u16* __restrict__ W1T,       // [128][128] bf16: W1T[j*128+k] = Wm1[k][j]
    const float* __restrict__ bm1,
    const float* __restrict__ lnw, const float* __restrict__ lnb,
    const float* __restrict__ Wm2, const float* __restrict__ bm2,
    double* __restrict__ partial, int M)
{
  __shared__ u16 Wsh[HD2][136];        // pad row to 272B: 2-way bank alias only (free)
  __shared__ double wsum[4];
  const int tid = threadIdx.x;
  const int lane = tid & 63, wv = tid >> 6;
  const int g = lane >> 4, cn = lane & 15;

  for (int i = tid; i < HD2 * 16; i += 256){
    int j = i >> 4, c = i & 15;
    *(uint4*)&Wsh[j][c * 8] = ((const uint4*)W1T)[i];
  }

  f32x4 b1v[8], c1v[8];
  float S1 = 0.f, C0 = 0.f;
#pragma unroll
  for (int jt = 0; jt < 8; ++jt){
    int j = jt * 16 + g * 4;
    float4 bb = *(const float4*)&bm1[j];
    float4 lw = *(const float4*)&lnw[j];
    float4 lb = *(const float4*)&lnb[j];
    float4 w2 = *(const float4*)&Wm2[j];
    b1v[jt][0] = bb.x; b1v[jt][1] = bb.y; b1v[jt][2] = bb.z; b1v[jt][3] = bb.w;
    c1v[jt][0] = lw.x * w2.x; c1v[jt][1] = lw.y * w2.y;
    c1v[jt][2] = lw.z * w2.z; c1v[jt][3] = lw.w * w2.w;
    S1 += c1v[jt][0] + c1v[jt][1] + c1v[jt][2] + c1v[jt][3];
    C0 += lb.x * w2.x + lb.y * w2.y + lb.z * w2.z + lb.w * w2.w;
  }
  S1 += __shfl_xor(S1, 16); S1 += __shfl_xor(S1, 32);
  C0 += __shfl_xor(C0, 16); C0 += __shfl_xor(C0, 32);
  const float bm2v = bm2[0];
  __syncthreads();

  double local = 0.0;
  const int stride = gridDim.x * 64;
  for (int base = blockIdx.x * 64 + wv * 16; base < M; base += stride){
    const int node = base + cn;
    const bool nv = node < M;
    f32x4 acc[8];
#pragma unroll
    for (int jt = 0; jt < 8; ++jt){ acc[jt][0]=0.f; acc[jt][1]=0.f; acc[jt][2]=0.f; acc[jt][3]=0.f; }
#pragma unroll
    for (int ks = 0; ks < 4; ++ks){
      bf16x8 bfv = {0,0,0,0,0,0,0,0};
      if (nv) bfv = *(const bf16x8*)(Xin + (size_t)node * HD2 + ks * 32 + g * 8);
#pragma unroll
      for (int jt = 0; jt < 8; ++jt){
        bf16x8 afr = *(const bf16x8*)&Wsh[jt * 16 + cn][ks * 32 + g * 8];
        acc[jt] = __builtin_amdgcn_mfma_f32_16x16x32_bf16(afr, bfv, acc[jt], 0, 0, 0);
      }
    }
    float s = 0.f;
#pragma unroll
    for (int jt = 0; jt < 8; ++jt){
#pragma unroll
      for (int r = 0; r < 4; ++r){
        acc[jt][r] += b1v[jt][r];
        s += acc[jt][r];
      }
    }
    s += __shfl_xor(s, 16); s += __shfl_xor(s, 32);
    const float mu = s * (1.0f / HD2);
    float vs = 0.f, d1 = 0.f;
#pragma unroll
    for (int jt = 0; jt < 8; ++jt){
#pragma unroll
      for (int r = 0; r < 4; ++r){
        float dv = acc[jt][r] - mu;
        vs = fmaf(dv, dv, vs);
        d1 = fmaf(acc[jt][r], c1v[jt][r], d1);
      }
    }
    vs += __shfl_xor(vs, 16); vs += __shfl_xor(vs, 32);
    d1 += __shfl_xor(d1, 16); d1 += __shfl_xor(d1, 32);
    const float rs = rsqrtf(vs * (1.0f / HD2) + 1e-5f);
    const float p = rs * (d1 - mu * S1) + C0 + bm2v;
    if (nv && g == 0) local += (double)p;
  }
#pragma unroll
  for (int off = 32; off > 0; off >>= 1) local += __shfl_xor(local, off);
  if (lane == 0) wsum[wv] = local;
  __syncthreads();
  if (tid == 0) partial[blockIdx.x] = wsum[0] + wsum[1] + wsum[2] + wsum[3];
}

// ---------------- final: sum 1024 f64 partials, dtype-robust output word ----------------
__global__ __launch_bounds__(256) void final_reduce_k(
    const double* __restrict__ P, u32* __restrict__ out)
{
  __shared__ double sm[256];
  const int tid = threadIdx.x;
  double s = P[tid] + P[tid + 256] + P[tid + 512] + P[tid + 768];
  sm[tid] = s;
  __syncthreads();
  for (int h = 128; h > 0; h >>= 1){
    if (tid < h) sm[tid] += sm[tid + h];
    __syncthreads();
  }
  if (tid == 0){
    float v = (float)(sm[0] * (1.0 / (2.0 * (double)NN)));
    u32 bf = f2bf(v);
    out[0] = (bf << 16) | bf;   // fp32 reader ~v; bf16 reader low half exact
  }
}

extern "C" void kernel_launch(void* const* d_in, const int* in_sizes, int n_in,
                              void* d_out, int out_size, void* d_ws, size_t ws_size,
                              hipStream_t stream)
{
  const float* x   = (const float*)d_in[0];
  const float* x1  = (const float*)d_in[1];
  const int* ei  = (const int*)d_in[2];
  const int* ei1 = (const int*)d_in[3];
  const float* Wg1 = (const float*)d_in[4];
  const float* bg1 = (const float*)d_in[5];
  const float* Wg2 = (const float*)d_in[6];
  const float* bg2 = (const float*)d_in[7];
  const float* Wl1 = (const float*)d_in[8];
  const float* bl1 = (const float*)d_in[9];
  const float* Wr1 = (const float*)d_in[10];
  const float* Wl2 = (const float*)d_in[11];
  const float* bl2 = (const float*)d_in[12];
  const float* Wr2 = (const float*)d_in[13];
  const float* Wm1 = (const float*)d_in[14];
  const float* bm1 = (const float*)d_in[15];
  const float* lnw = (const float*)d_in[16];
  const float* lnb = (const float*)d_in[17];
  const float* Wm2 = (const float*)d_in[18];
  const float* bm2 = (const float*)d_in[19];

  const int* src1 = ei,  * dst1 = ei + EE;
  const int* src2 = ei1, * dst2 = ei1 + EE;

  // ---- workspace layout (bf16 node features + CSR + partials), ~264 MB ----
  u16* U0 = (u16*)d_ws;                        // XW1 -> X0     [NN*HH]
  u16* U1 = U0 + (size_t)NN * HH;              // XW2 -> G1
  u16* U2 = U1 + (size_t)NN * HH;              // H1  -> M1
  u16* U3 = U2 + (size_t)NN * HH;              // H2  -> M2
  u16* U4 = U3 + (size_t)NN * HH;              // S1 [NN*HD2]
  u16* U5 = U4 + (size_t)NN * HD2;             // S2 (contiguous after S1)
  u16* WG1T = U5 + (size_t)NN * HD2;           // [HH][FF]
  u16* WG2T = WG1T + HH * FF;
  u16* WL1T = WG2T + HH * FF;                  // [HD2][HH]
  u16* WR1T = WL1T + HD2 * HH;
  u16* WL2T = WR1T + HD2 * HH;
  u16* WR2T = WL2T + HD2 * HH;
  int* deg1 = (int*)(WR2T + HD2 * HH);
  int* deg2 = deg1 + NN;
  int* fill1 = deg2 + NN;
  int* fill2 = fill1 + NN;
  int* rp1 = fill2 + NN;
  int* rp2 = rp1 + NN;
  int* aux1 = rp2 + NN;
  int* aux2 = aux1 + 128;
  int* csr1 = aux2 + 128;
  int* csr2 = csr1 + EE;
  double* P = (double*)(csr2 + EE);            // 1024 doubles (8B-aligned)
  u16* WM1T = U0;                              // reuse U0 after sage GEMMs (stream-serial)

  const int eblk = (EE + 255) / 256;
  const int nchunks = (NN + 1023) / 1024;      // 98

  // ---- CSR build (both graphs) ----
  zero_int_k<<<512, 256, 0, stream>>>(deg1, 4 * NN);   // deg1,deg2,fill1,fill2
  count_deg_k<<<eblk, 256, 0, stream>>>(dst1, deg1, EE);
  count_deg_k<<<eblk, 256, 0, stream>>>(dst2, deg2, EE);
  scan1_k<<<nchunks, 256, 0, stream>>>(deg1, rp1, aux1, NN);
  scan1_k<<<nchunks, 256, 0, stream>>>(deg2, rp2, aux2, NN);
  scan2_k<<<1, 64, 0, stream>>>(aux1, nchunks);
  scan2_k<<<1, 64, 0, stream>>>(aux2, nchunks);
  scan3_k<<<(NN + 255) / 256, 256, 0, stream>>>(rp1, aux1, NN);
  scan3_k<<<(NN + 255) / 256, 256, 0, stream>>>(rp2, aux2, NN);
  csr_fill_k<<<eblk, 256, 0, stream>>>(src1, dst1, rp1, fill1, csr1, EE);
  csr_fill_k<<<eblk, 256, 0, stream>>>(src2, dst2, rp2, fill2, csr2, EE);

  // ---- weight convert+transpose ----
  wtcvt_k<<<512, 256, 0, stream>>>(Wg1, WG1T, FF, HH - 1, 8, FF * HH);
  wtcvt_k<<<512, 256, 0, stream>>>(Wg2, WG2T, FF, HH - 1, 8, FF * HH);
  wtcvt_k<<<128, 256, 0, stream>>>(Wl1, WL1T, HH, HD2 - 1, 7, HH * HD2);
  wtcvt_k<<<128, 256, 0, stream>>>(Wr1, WR1T, HH, HD2 - 1, 7, HH * HD2);
  wtcvt_k<<<128, 256, 0, stream>>>(Wl2, WL2T, HH, HD2 - 1, 7, HH * HD2);
  wtcvt_k<<<128, 256, 0, stream>>>(Wr2, WR2T, HH, HD2 - 1, 7, HH * HD2);

  // ---- GCN linear (MFMA, depth-2 pipelined) ----
  dim3 ggrid((NN + 127) / 128, HH / 128);      // (782, 2)
  gemm_xw_k<<<ggrid, 256, 0, stream>>>(x,  WG1T, U0, NN);
  gemm_xw_k<<<ggrid, 256, 0, stream>>>(x1, WG2T, U1, NN);

  // ---- GCN aggregate (CSR gather, fused self-loop + bias) ----
  gcn_agg_k<<<NN / 4, 256, 0, stream>>>(U0, rp1, deg1, csr1, bg1, U2, NN);
  gcn_agg_k<<<NN / 4, 256, 0, stream>>>(U1, rp2, deg2, csr2, bg2, U3, NN);

  // ---- combine ----
  combine_k<<<NN * HH / 512, 256, 0, stream>>>((u32*)U0, (u32*)U1, (const u32*)U2, (const u32*)U3);

  // ---- SAGE mean aggregate (CSR gather, fused mean) ----
  sage_mean_k<<<NN / 4, 256, 0, stream>>>(U0, rp1, deg1, csr1, U2, NN);
  sage_mean_k<<<NN / 4, 256, 0, stream>>>(U1, rp2, deg2, csr2, U3, NN);

  // ---- SAGE linear (MFMA, two K-passes) + relu ----
  sage_gemm_k<<<(NN + 127) / 128, 256, 0, stream>>>(U2, U0, WL1T, WR1T, bl1, U4, NN);
  sage_gemm_k<<<(NN + 127) / 128, 256, 0, stream>>>(U3, U1, WL2T, WR2T, bl2, U5, NN);

  // ---- Wm1^T bf16 (into U0, free after the sage GEMMs) ----
  wtcvt_k<<<64, 256, 0, stream>>>(Wm1, WM1T, HD2, HD2 - 1, 7, HD2 * HD2);

  // ---- fused MLP + LN + reduce over both halves (U4||U5 contiguous, M = 2N) ----
  mlp_mfma_k<<<1024, 256, 0, stream>>>(U4, WM1T, bm1, lnw, lnb, Wm2, bm2, P, 2 * NN);

  final_reduce_k<<<1, 256, 0, stream>>>(P, (u32*)d_out);
}